// Round 10
// baseline (439.880 us; speedup 1.0000x reference)
//
#include <hip/hip_runtime.h>
#include <stdint.h>

#define N_ALL   16384
#define NPOINT  4096
#define KNN_K   32
#define BATCH   2
#define P_TOT   (BATCH*NPOINT*KNN_K)   /* 262144 */
#define P_TOTF  262144.0f
#define EPSV    1e-5f

typedef __attribute__((ext_vector_type(8))) short bf16x8;
typedef __attribute__((ext_vector_type(4))) float f32x4;

// ---- all scratch in module-static device memory; d_ws untouched ----
__device__ unsigned short g_knn[P_TOT];                                   // 512 KB
__device__ float g_xn[BATCH*N_ALL];                                       // 128 KB
__device__ __attribute__((aligned(16))) short g_ptb[BATCH*N_ALL*64];      // 4 MB  [b,n][64c] bf16
__device__ __attribute__((aligned(16))) short g_x0b[(size_t)P_TOT*64];    // 32 MB [p][64] bf16
__device__ __attribute__((aligned(16))) short g_x1b[(size_t)P_TOT*64];    // 32 MB
__device__ __attribute__((aligned(16))) float g_ymax[8192*128];           // 4 MB [sg][c]
__device__ __attribute__((aligned(16))) float g_ymin[8192*128];           // 4 MB
__device__ __attribute__((aligned(16))) short g_Wb0[4*3*64*8];            // swizzled A-frags
__device__ __attribute__((aligned(16))) short g_Wb1[4*2*64*8];
__device__ __attribute__((aligned(16))) short g_Wb2[8*2*64*8];
__device__ float g_part0[128], g_part1[128], g_part2[256];

__device__ __forceinline__ float b2f(short s) {
  union { unsigned u; float f; } v; v.u = ((unsigned)(unsigned short)s) << 16; return v.f;
}
__device__ __forceinline__ short f2b(float f) {
  union { float f; unsigned u; } v; v.f = f;
  unsigned u = v.u;
  u += 0x7FFFu + ((u >> 16) & 1u);
  return (short)(u >> 16);
}
__device__ __forceinline__ unsigned long long shflup64(unsigned long long v) {
  int lo = __shfl_up((int)(unsigned)(v & 0xFFFFFFFFULL), 1, 64);
  int hi = __shfl_up((int)(unsigned)(v >> 32), 1, 64);
  return (((unsigned long long)(unsigned)hi) << 32) | (unsigned)lo;
}
__device__ __forceinline__ unsigned long long rdlane64(unsigned long long v, int j) {
  unsigned hi = (unsigned)__builtin_amdgcn_readlane((int)(unsigned)(v >> 32), j);
  unsigned lo = (unsigned)__builtin_amdgcn_readlane((int)(unsigned)(v & 0xFFFFFFFFULL), j);
  return (((unsigned long long)hi) << 32) | lo;
}

// ---------------- new_xyz passthrough copy ----------------
__global__ void k_newxyz(const float* __restrict__ xyz, float* __restrict__ out) {
  int i = blockIdx.x * 256 + threadIdx.x;   // < 24576
  int s = i & 4095;
  int c = (i >> 12) % 3;
  int b = i / 12288;
  out[i] = xyz[(b * 3 + c) * N_ALL + s];
}

// ---------------- prep: swizzle weights to per-lane MFMA A-frags, zero parts ----------------
__global__ void k_prep(const float* __restrict__ W0, const float* __restrict__ W1,
                       const float* __restrict__ W2) {
  int t = threadIdx.x;
  for (int i = t; i < 4 * 3 * 64 * 8; i += 256) {
    int j = i & 7, lane = (i >> 3) & 63, rest = i >> 9;
    int kt = rest % 3, mt = rest / 3;
    int m = 16 * mt + (lane & 15);
    int k = 32 * kt + (lane >> 4) * 8 + j;
    float v = 0.f;
    if (k < 64) v = W0[m * 67 + 3 + k];
    else if (k < 67) v = W0[m * 67 + (k - 64)];
    g_Wb0[i] = f2b(v);
  }
  for (int i = t; i < 4 * 2 * 64 * 8; i += 256) {
    int j = i & 7, lane = (i >> 3) & 63;
    int kt = (i >> 9) & 1, mt = i >> 10;
    int m = 16 * mt + (lane & 15);
    int k = 32 * kt + (lane >> 4) * 8 + j;
    g_Wb1[i] = f2b(W1[m * 64 + k]);
  }
  for (int i = t; i < 8 * 2 * 64 * 8; i += 256) {
    int j = i & 7, lane = (i >> 3) & 63;
    int kt = (i >> 9) & 1, mt = i >> 10;
    int m = 16 * mt + (lane & 15);
    int k = 32 * kt + (lane >> 4) * 8 + j;
    g_Wb2[i] = f2b(W2[m * 64 + k]);
  }
  if (t < 128) { g_part0[t] = 0.f; g_part1[t] = 0.f; }
  g_part2[t] = 0.f;
}

// ---------------- transpose points [b][c][n] -> g_ptb [b,n][c] bf16 ----------------
__global__ __launch_bounds__(256) void k_tpose(const float* __restrict__ points) {
  __shared__ float tile[64][65];
  int b  = blockIdx.x >> 8;
  int n0 = (blockIdx.x & 255) << 6;
#pragma unroll
  for (int r = 0; r < 16; r++) {
    int lin = r * 256 + threadIdx.x;
    int c = lin >> 6, nn = lin & 63;
    tile[c][nn] = points[((size_t)(b * 64 + c)) * N_ALL + n0 + nn];
  }
  __syncthreads();
#pragma unroll
  for (int r = 0; r < 16; r++) {
    int lin = r * 256 + threadIdx.x;
    int nn = lin >> 6, c = lin & 63;
    g_ptb[((size_t)(b * N_ALL + n0 + nn)) * 64 + c] = f2b(tile[c][nn]);
  }
}

// ---------------- per-point squared norms (exact reference op order) ----------------
__global__ void k_xn(const float* __restrict__ xyz) {
#pragma clang fp contract(off)
  int i = blockIdx.x * 256 + threadIdx.x;   // < 32768
  int b = i >> 14, n = i & 16383;
  const float* xb = xyz + b * 3 * N_ALL;
  float x = xb[n], y = xb[N_ALL + n], z = xb[2 * N_ALL + n];
  g_xn[i] = x * x + y * y + z * z;
}

// ---------------- KNN: f32 fast filter, u64-exact insert, readlane broadcasts ----------------
__global__ __launch_bounds__(256) void k_knn(const float* __restrict__ xyz) {
#pragma clang fp contract(off)
  int q = blockIdx.x * 4 + (threadIdx.x >> 6);   // 0..8191
  int b = q >> 12, s = q & 4095;
  int lane = threadIdx.x & 63;
  const float* xb = xyz + b * 3 * N_ALL;
  const float* xnb = g_xn + (b << 14);
  float qx = xb[s], qy = xb[N_ALL + s], qz = xb[2 * N_ALL + s];
  float qn = xnb[s];

  unsigned long long list = ~0ULL;    // lanes 0..31: sorted (keybits<<32|idx)
  unsigned long long worst = ~0ULL;   // broadcast copy of list[31]
  float worst_d = __builtin_inff();   // float distance of list[31] (inf while sentinel)

  for (int n0 = 0; n0 < N_ALL; n0 += 256) {
    float d[4];
#pragma unroll
    for (int t = 0; t < 4; t++) {
      int n = n0 + (t << 6) + lane;
      float x = xb[n];
      float y = xb[N_ALL + n];
      float z = xb[2 * N_ALL + n];
      float dt = qx * x + qy * y + qz * z;
      d[t] = (qn + xnb[n]) - 2.0f * dt;
    }
    float md = fminf(fminf(d[0], d[1]), fminf(d[2], d[3]));
    if (__ballot(md <= worst_d)) {
#pragma unroll
      for (int t = 0; t < 4; t++) {
        unsigned du = __float_as_uint(d[t]);
        du ^= ((unsigned)(((int)du) >> 31)) | 0x80000000u;   // order-preserving map
        unsigned long long cand = (((unsigned long long)du) << 32)
                                | (unsigned)(n0 + (t << 6) + lane);
        while (true) {
          unsigned long long ball = __ballot(cand < worst);
          if (!ball) break;
          int j = (int)__builtin_ctzll(ball);
          unsigned long long bk = rdlane64(cand, j);
          if (lane == j) cand = ~0ULL;                 // retire
          unsigned long long up = shflup64(list);
          unsigned long long lm = __ballot(bk < list) & 0xFFFFFFFFULL;
          int pos = (int)__builtin_ctzll(lm);          // bit31 guaranteed set
          if (lane == pos) list = bk;
          else if (lane > pos && lane < 32) list = up;
          worst = rdlane64(list, 31);
          unsigned wh = (unsigned)(worst >> 32);
          worst_d = (wh == 0xFFFFFFFFu) ? __builtin_inff()
                    : __uint_as_float(wh ^ ((wh & 0x80000000u) ? 0x80000000u : 0xFFFFFFFFu));
        }
      }
    }
  }
  if (lane < 32)
    g_knn[(q << 5) | lane] = (unsigned short)(list & 0xFFFF);
}

// ---------------- layer0: gather to LDS, MFMA K=96 -> x0 bf16, fused stats0 ----------------
__global__ __launch_bounds__(256) void k_l0(const float* __restrict__ xyz) {
  __shared__ short feats[256][104];   // row 208B: 16B-aligned
  __shared__ float bsum[4][64], bsq[4][64];
  int t = threadIdx.x;
  int p0 = blockIdx.x * 256;
  {
    int p = p0 + t;
    int idx = g_knn[p];
    int s = (p >> 5) & 4095;
    int b = p >> 17;
    const short* src = g_ptb + ((size_t)((b << 14) + idx) << 6);
#pragma unroll
    for (int i = 0; i < 8; i++)
      ((int4*)&feats[t][0])[i] = ((const int4*)src)[i];
    const float* xb = xyz + b * 3 * N_ALL;
    feats[t][64] = f2b(xb[idx] - xb[s]);
    feats[t][65] = f2b(xb[N_ALL + idx] - xb[N_ALL + s]);
    feats[t][66] = f2b(xb[2 * N_ALL + idx] - xb[2 * N_ALL + s]);
#pragma unroll
    for (int c = 67; c < 96; c++) feats[t][c] = 0;
  }
  __syncthreads();
  int lane = t & 63, wv = t >> 6;
  int l15 = lane & 15, quad = lane >> 4;
  bf16x8 A[4][3];
#pragma unroll
  for (int mt = 0; mt < 4; mt++)
#pragma unroll
    for (int kt = 0; kt < 3; kt++)
      A[mt][kt] = *(const bf16x8*)(g_Wb0 + (((mt * 3 + kt) * 64 + lane) << 3));
  f32x4 C[4][4];
#pragma unroll
  for (int mt = 0; mt < 4; mt++)
#pragma unroll
    for (int nt = 0; nt < 4; nt++) C[mt][nt] = 0.f;
#pragma unroll
  for (int kt = 0; kt < 3; kt++)
#pragma unroll
    for (int nt = 0; nt < 4; nt++) {
      bf16x8 B = *(const bf16x8*)(&feats[wv * 64 + nt * 16 + l15][kt * 32 + quad * 8]);
#pragma unroll
      for (int mt = 0; mt < 4; mt++)
        C[mt][nt] = __builtin_amdgcn_mfma_f32_16x16x32_bf16(A[mt][kt], B, C[mt][nt], 0, 0, 0);
    }
#pragma unroll
  for (int mt = 0; mt < 4; mt++) {
#pragma unroll
    for (int nt = 0; nt < 4; nt++) {
      int p = p0 + wv * 64 + nt * 16 + l15;
      int c0 = mt * 16 + quad * 4;
      short4 o;
      o.x = f2b(C[mt][nt][0]); o.y = f2b(C[mt][nt][1]);
      o.z = f2b(C[mt][nt][2]); o.w = f2b(C[mt][nt][3]);
      *(short4*)(g_x0b + ((size_t)p << 6) + c0) = o;
    }
    float S[4], Q[4];
#pragma unroll
    for (int i = 0; i < 4; i++) {
      S[i] = C[mt][0][i] + C[mt][1][i] + C[mt][2][i] + C[mt][3][i];
      Q[i] = C[mt][0][i]*C[mt][0][i] + C[mt][1][i]*C[mt][1][i]
           + C[mt][2][i]*C[mt][2][i] + C[mt][3][i]*C[mt][3][i];
    }
#pragma unroll
    for (int m = 1; m <= 8; m <<= 1)
#pragma unroll
      for (int i = 0; i < 4; i++) {
        S[i] += __shfl_xor(S[i], m, 64);
        Q[i] += __shfl_xor(Q[i], m, 64);
      }
    if (l15 == 0)
#pragma unroll
      for (int i = 0; i < 4; i++) {
        bsum[wv][mt * 16 + quad * 4 + i] = S[i];
        bsq[wv][mt * 16 + quad * 4 + i]  = Q[i];
      }
  }
  __syncthreads();
  if (t < 64) {
    atomicAdd(g_part0 + t,      bsum[0][t] + bsum[1][t] + bsum[2][t] + bsum[3][t]);
    atomicAdd(g_part0 + 64 + t, bsq[0][t]  + bsq[1][t]  + bsq[2][t]  + bsq[3][t]);
  }
}

// ---------------- layer1: BN0+leaky, MFMA K=64 -> x1 bf16, fused stats1 ----------------
__global__ __launch_bounds__(256) void k_l1(const float* __restrict__ g0,
                                            const float* __restrict__ b0) {
  __shared__ float scA[64], shA[64];
  __shared__ float bsum[4][64], bsq[4][64];
  int t = threadIdx.x;
  if (t < 64) {
    float m = g_part0[t] / P_TOTF;
    float v = g_part0[64 + t] / P_TOTF - m * m;
    float sc = g0[t] / sqrtf(v + EPSV);
    scA[t] = sc; shA[t] = b0[t] - m * sc;
  }
  __syncthreads();
  int lane = t & 63, wv = t >> 6;
  int l15 = lane & 15, quad = lane >> 4;
  int p0 = blockIdx.x * 256 + wv * 64;
  float scv[2][8], shv[2][8];
#pragma unroll
  for (int kt = 0; kt < 2; kt++)
#pragma unroll
    for (int j = 0; j < 8; j++) {
      int c = kt * 32 + quad * 8 + j;
      scv[kt][j] = scA[c]; shv[kt][j] = shA[c];
    }
  bf16x8 A[4][2];
#pragma unroll
  for (int mt = 0; mt < 4; mt++)
#pragma unroll
    for (int kt = 0; kt < 2; kt++)
      A[mt][kt] = *(const bf16x8*)(g_Wb1 + (((mt * 2 + kt) * 64 + lane) << 3));
  f32x4 C[4][4];
#pragma unroll
  for (int mt = 0; mt < 4; mt++)
#pragma unroll
    for (int nt = 0; nt < 4; nt++) C[mt][nt] = 0.f;
#pragma unroll
  for (int kt = 0; kt < 2; kt++)
#pragma unroll
    for (int nt = 0; nt < 4; nt++) {
      const short* src = g_x0b + (((size_t)(p0 + nt * 16 + l15)) << 6) + kt * 32 + quad * 8;
      bf16x8 raw = *(const bf16x8*)src;
      bf16x8 B;
#pragma unroll
      for (int j = 0; j < 8; j++) {
        float a = b2f(raw[j]) * scv[kt][j] + shv[kt][j];
        a = fmaxf(a, 0.1f * a);
        B[j] = f2b(a);
      }
#pragma unroll
      for (int mt = 0; mt < 4; mt++)
        C[mt][nt] = __builtin_amdgcn_mfma_f32_16x16x32_bf16(A[mt][kt], B, C[mt][nt], 0, 0, 0);
    }
#pragma unroll
  for (int mt = 0; mt < 4; mt++) {
#pragma unroll
    for (int nt = 0; nt < 4; nt++) {
      int p = p0 + nt * 16 + l15;
      int c0 = mt * 16 + quad * 4;
      short4 o;
      o.x = f2b(C[mt][nt][0]); o.y = f2b(C[mt][nt][1]);
      o.z = f2b(C[mt][nt][2]); o.w = f2b(C[mt][nt][3]);
      *(short4*)(g_x1b + ((size_t)p << 6) + c0) = o;
    }
    float S[4], Q[4];
#pragma unroll
    for (int i = 0; i < 4; i++) {
      S[i] = C[mt][0][i] + C[mt][1][i] + C[mt][2][i] + C[mt][3][i];
      Q[i] = C[mt][0][i]*C[mt][0][i] + C[mt][1][i]*C[mt][1][i]
           + C[mt][2][i]*C[mt][2][i] + C[mt][3][i]*C[mt][3][i];
    }
#pragma unroll
    for (int m = 1; m <= 8; m <<= 1)
#pragma unroll
      for (int i = 0; i < 4; i++) {
        S[i] += __shfl_xor(S[i], m, 64);
        Q[i] += __shfl_xor(Q[i], m, 64);
      }
    if (l15 == 0)
#pragma unroll
      for (int i = 0; i < 4; i++) {
        bsum[wv][mt * 16 + quad * 4 + i] = S[i];
        bsq[wv][mt * 16 + quad * 4 + i]  = Q[i];
      }
  }
  __syncthreads();
  if (t < 64) {
    atomicAdd(g_part1 + t,      bsum[0][t] + bsum[1][t] + bsum[2][t] + bsum[3][t]);
    atomicAdd(g_part1 + 64 + t, bsq[0][t]  + bsq[1][t]  + bsq[2][t]  + bsq[3][t]);
  }
}

// ---------------- layer2: BN1+leaky, MFMA K=64 M=128, fused k-max/min + stats2 ----------------
__global__ __launch_bounds__(256) void k_l2(const float* __restrict__ g1,
                                            const float* __restrict__ b1) {
  __shared__ float scA[64], shA[64];
  __shared__ float bsum[2][128], bsq[2][128];
  int t = threadIdx.x;
  if (t < 64) {
    float m = g_part1[t] / P_TOTF;
    float v = g_part1[64 + t] / P_TOTF - m * m;
    float sc = g1[t] / sqrtf(v + EPSV);
    scA[t] = sc; shA[t] = b1[t] - m * sc;
  }
  __syncthreads();
  int lane = t & 63, wv = t >> 6;
  int l15 = lane & 15, quad = lane >> 4;
  int chh = wv & 1;                      // channel half
  int ph  = wv >> 1;                     // point half
  int p0 = blockIdx.x * 128 + ph * 64;
  float scv[2][8], shv[2][8];
#pragma unroll
  for (int kt = 0; kt < 2; kt++)
#pragma unroll
    for (int j = 0; j < 8; j++) {
      int c = kt * 32 + quad * 8 + j;
      scv[kt][j] = scA[c]; shv[kt][j] = shA[c];
    }
  bf16x8 A[4][2];
#pragma unroll
  for (int mt = 0; mt < 4; mt++)
#pragma unroll
    for (int kt = 0; kt < 2; kt++)
      A[mt][kt] = *(const bf16x8*)(g_Wb2 + ((((4 * chh + mt) * 2 + kt) * 64 + lane) << 3));
  f32x4 C[4][4];
#pragma unroll
  for (int mt = 0; mt < 4; mt++)
#pragma unroll
    for (int nt = 0; nt < 4; nt++) C[mt][nt] = 0.f;
#pragma unroll
  for (int kt = 0; kt < 2; kt++)
#pragma unroll
    for (int nt = 0; nt < 4; nt++) {
      const short* src = g_x1b + (((size_t)(p0 + nt * 16 + l15)) << 6) + kt * 32 + quad * 8;
      bf16x8 raw = *(const bf16x8*)src;
      bf16x8 B;
#pragma unroll
      for (int j = 0; j < 8; j++) {
        float a = b2f(raw[j]) * scv[kt][j] + shv[kt][j];
        a = fmaxf(a, 0.1f * a);
        B[j] = f2b(a);
      }
#pragma unroll
      for (int mt = 0; mt < 4; mt++)
        C[mt][nt] = __builtin_amdgcn_mfma_f32_16x16x32_bf16(A[mt][kt], B, C[mt][nt], 0, 0, 0);
    }
  // fused per-k-group max/min (group g: nt 2g,2g+1 + 16 l15 lanes) and stats
  int sgb = blockIdx.x * 4 + ph * 2;
#pragma unroll
  for (int mt = 0; mt < 4; mt++) {
    float S[4], Q[4], MX0[4], MN0[4], MX1[4], MN1[4];
#pragma unroll
    for (int i = 0; i < 4; i++) {
      S[i] = C[mt][0][i] + C[mt][1][i] + C[mt][2][i] + C[mt][3][i];
      Q[i] = C[mt][0][i]*C[mt][0][i] + C[mt][1][i]*C[mt][1][i]
           + C[mt][2][i]*C[mt][2][i] + C[mt][3][i]*C[mt][3][i];
      MX0[i] = fmaxf(C[mt][0][i], C[mt][1][i]); MN0[i] = fminf(C[mt][0][i], C[mt][1][i]);
      MX1[i] = fmaxf(C[mt][2][i], C[mt][3][i]); MN1[i] = fminf(C[mt][2][i], C[mt][3][i]);
    }
#pragma unroll
    for (int m = 1; m <= 8; m <<= 1)
#pragma unroll
      for (int i = 0; i < 4; i++) {
        S[i] += __shfl_xor(S[i], m, 64);
        Q[i] += __shfl_xor(Q[i], m, 64);
        MX0[i] = fmaxf(MX0[i], __shfl_xor(MX0[i], m, 64));
        MN0[i] = fminf(MN0[i], __shfl_xor(MN0[i], m, 64));
        MX1[i] = fmaxf(MX1[i], __shfl_xor(MX1[i], m, 64));
        MN1[i] = fminf(MN1[i], __shfl_xor(MN1[i], m, 64));
      }
    if (l15 == 0) {
      int ch = (4 * chh + mt) * 16 + quad * 4;
#pragma unroll
      for (int i = 0; i < 4; i++) {
        bsum[ph][ch + i] = S[i];
        bsq[ph][ch + i]  = Q[i];
      }
      float4 a0, a1, n0v, n1v;
      a0.x = MX0[0]; a0.y = MX0[1]; a0.z = MX0[2]; a0.w = MX0[3];
      a1.x = MX1[0]; a1.y = MX1[1]; a1.z = MX1[2]; a1.w = MX1[3];
      n0v.x = MN0[0]; n0v.y = MN0[1]; n0v.z = MN0[2]; n0v.w = MN0[3];
      n1v.x = MN1[0]; n1v.y = MN1[1]; n1v.z = MN1[2]; n1v.w = MN1[3];
      *(float4*)&g_ymax[(size_t)(sgb + 0) * 128 + ch] = a0;
      *(float4*)&g_ymax[(size_t)(sgb + 1) * 128 + ch] = a1;
      *(float4*)&g_ymin[(size_t)(sgb + 0) * 128 + ch] = n0v;
      *(float4*)&g_ymin[(size_t)(sgb + 1) * 128 + ch] = n1v;
    }
  }
  __syncthreads();
  if (t < 128) {
    atomicAdd(g_part2 + t,       bsum[0][t] + bsum[1][t]);
    atomicAdd(g_part2 + 128 + t, bsq[0][t]  + bsq[1][t]);
  }
}

// ---------------- epilogue: BN2+leaky over k-extrema, LDS transpose, write f32 ----------------
__global__ __launch_bounds__(256) void k_epi(const float* __restrict__ g2,
                                             const float* __restrict__ b2,
                                             float* __restrict__ out) {
  __shared__ float lmax[32][129], lmin[32][129];
  __shared__ float scA[128], shA[128];
  int t = threadIdx.x;
  if (t < 128) {
    float m = g_part2[t] / P_TOTF;
    float v = g_part2[128 + t] / P_TOTF - m * m;
    float sc = g2[t] / sqrtf(v + EPSV);
    scA[t] = sc; shA[t] = b2[t] - m * sc;
  }
  int sg0 = blockIdx.x * 32;   // 256 blocks
#pragma unroll
  for (int i = 0; i < 16; i++) {
    int idx = i * 256 + t;
    int r = idx >> 7, c = idx & 127;
    lmax[r][c] = g_ymax[(size_t)(sg0 + r) * 128 + c];
    lmin[r][c] = g_ymin[(size_t)(sg0 + r) * 128 + c];
  }
  __syncthreads();
  int c = t >> 1, h = t & 1;
  float sc = scA[c], sh = shA[c];
  int b = sg0 >> 12, s0 = (sg0 & 4095) + h * 16;
  float* po = out + 24576 + (((size_t)(b * 128 + c)) << 12) + s0;
#pragma unroll
  for (int jj = 0; jj < 4; jj++) {
    float4 r4;
#pragma unroll
    for (int e = 0; e < 4; e++) {
      int r = h * 16 + jj * 4 + e;
      float v = (sc >= 0.f) ? lmax[r][c] : lmin[r][c];
      float a = v * sc + sh;
      a = fmaxf(a, 0.1f * a);
      ((float*)&r4)[e] = a;
    }
    ((float4*)po)[jj] = r4;
  }
}

extern "C" void kernel_launch(void* const* d_in, const int* in_sizes, int n_in,
                              void* d_out, int out_size, void* d_ws, size_t ws_size,
                              hipStream_t stream) {
  (void)in_sizes; (void)n_in; (void)out_size; (void)d_ws; (void)ws_size;
  const float* xyz    = (const float*)d_in[0];
  const float* points = (const float*)d_in[1];
  const float* W0     = (const float*)d_in[2];
  const float* W1     = (const float*)d_in[3];
  const float* W2     = (const float*)d_in[4];
  const float* g0     = (const float*)d_in[5];
  const float* b0     = (const float*)d_in[6];
  const float* g1     = (const float*)d_in[7];
  const float* b1     = (const float*)d_in[8];
  const float* g2     = (const float*)d_in[9];
  const float* b2     = (const float*)d_in[10];
  float* out = (float*)d_out;

  hipLaunchKernelGGL(k_newxyz, dim3(96),   dim3(256), 0, stream, xyz, out);
  hipLaunchKernelGGL(k_prep,   dim3(1),    dim3(256), 0, stream, W0, W1, W2);
  hipLaunchKernelGGL(k_tpose,  dim3(512),  dim3(256), 0, stream, points);
  hipLaunchKernelGGL(k_xn,     dim3(128),  dim3(256), 0, stream, xyz);
  hipLaunchKernelGGL(k_knn,    dim3(2048), dim3(256), 0, stream, xyz);
  hipLaunchKernelGGL(k_l0,     dim3(1024), dim3(256), 0, stream, xyz);
  hipLaunchKernelGGL(k_l1,     dim3(1024), dim3(256), 0, stream, g0, b0);
  hipLaunchKernelGGL(k_l2,     dim3(2048), dim3(256), 0, stream, g1, b1);
  hipLaunchKernelGGL(k_epi,    dim3(256),  dim3(256), 0, stream, g2, b2, out);
}

// Round 11
// 393.536 us; speedup vs baseline: 1.1178x; 1.1178x over previous
//
#include <hip/hip_runtime.h>
#include <stdint.h>

#define N_ALL   16384
#define NPOINT  4096
#define KNN_K   32
#define BATCH   2
#define P_TOT   (BATCH*NPOINT*KNN_K)   /* 262144 */
#define P_TOTF  262144.0f
#define EPSV    1e-5f

typedef __attribute__((ext_vector_type(8))) short bf16x8;
typedef __attribute__((ext_vector_type(4))) float f32x4;

// ---- all scratch in module-static device memory; d_ws untouched ----
__device__ unsigned short g_knn[P_TOT];                                   // 512 KB
__device__ float g_xn[BATCH*N_ALL];                                       // 128 KB
__device__ __attribute__((aligned(16))) short g_ptb[BATCH*N_ALL*64];      // 4 MB  [b,n][64c] bf16
__device__ __attribute__((aligned(16))) short g_x0b[(size_t)P_TOT*64];    // 32 MB [p][64] bf16
__device__ __attribute__((aligned(16))) short g_x1b[(size_t)P_TOT*64];    // 32 MB
__device__ __attribute__((aligned(16))) short g_x2b[(size_t)P_TOT*128];   // 64 MB
__device__ __attribute__((aligned(16))) short g_Wb0[4*3*64*8];            // swizzled A-frags
__device__ __attribute__((aligned(16))) short g_Wb1[4*2*64*8];
__device__ __attribute__((aligned(16))) short g_Wb2[8*2*64*8];
__device__ float g_part0[128], g_part1[128], g_part2[256];

__device__ __forceinline__ float b2f(short s) {
  union { unsigned u; float f; } v; v.u = ((unsigned)(unsigned short)s) << 16; return v.f;
}
__device__ __forceinline__ short f2b(float f) {
  union { float f; unsigned u; } v; v.f = f;
  unsigned u = v.u;
  u += 0x7FFFu + ((u >> 16) & 1u);
  return (short)(u >> 16);
}
__device__ __forceinline__ unsigned long long shflup64(unsigned long long v) {
  int lo = __shfl_up((int)(unsigned)(v & 0xFFFFFFFFULL), 1, 64);
  int hi = __shfl_up((int)(unsigned)(v >> 32), 1, 64);
  return (((unsigned long long)(unsigned)hi) << 32) | (unsigned)lo;
}
__device__ __forceinline__ unsigned long long rdlane64(unsigned long long v, int j) {
  unsigned hi = (unsigned)__builtin_amdgcn_readlane((int)(unsigned)(v >> 32), j);
  unsigned lo = (unsigned)__builtin_amdgcn_readlane((int)(unsigned)(v & 0xFFFFFFFFULL), j);
  return (((unsigned long long)hi) << 32) | lo;
}

// ---------------- new_xyz copy + per-point squared norms (fused) ----------------
__global__ void k_init(const float* __restrict__ xyz, float* __restrict__ out) {
#pragma clang fp contract(off)
  int i = blockIdx.x * 256 + threadIdx.x;   // < 32768
  if (i < 24576) {
    int s = i & 4095;
    int c = (i >> 12) % 3;
    int b = i / 12288;
    out[i] = xyz[(b * 3 + c) * N_ALL + s];
  }
  int b = i >> 14, n = i & 16383;
  const float* xb = xyz + b * 3 * N_ALL;
  float x = xb[n], y = xb[N_ALL + n], z = xb[2 * N_ALL + n];
  g_xn[i] = x * x + y * y + z * z;
}

// ---------------- prep: swizzle weights to per-lane MFMA A-frags, zero parts ----------------
__global__ void k_prep(const float* __restrict__ W0, const float* __restrict__ W1,
                       const float* __restrict__ W2) {
  int t = threadIdx.x;
  for (int i = t; i < 4 * 3 * 64 * 8; i += 256) {
    int j = i & 7, lane = (i >> 3) & 63, rest = i >> 9;
    int kt = rest % 3, mt = rest / 3;
    int m = 16 * mt + (lane & 15);
    int k = 32 * kt + (lane >> 4) * 8 + j;
    float v = 0.f;
    if (k < 64) v = W0[m * 67 + 3 + k];
    else if (k < 67) v = W0[m * 67 + (k - 64)];
    g_Wb0[i] = f2b(v);
  }
  for (int i = t; i < 4 * 2 * 64 * 8; i += 256) {
    int j = i & 7, lane = (i >> 3) & 63;
    int kt = (i >> 9) & 1, mt = i >> 10;
    int m = 16 * mt + (lane & 15);
    int k = 32 * kt + (lane >> 4) * 8 + j;
    g_Wb1[i] = f2b(W1[m * 64 + k]);
  }
  for (int i = t; i < 8 * 2 * 64 * 8; i += 256) {
    int j = i & 7, lane = (i >> 3) & 63;
    int kt = (i >> 9) & 1, mt = i >> 10;
    int m = 16 * mt + (lane & 15);
    int k = 32 * kt + (lane >> 4) * 8 + j;
    g_Wb2[i] = f2b(W2[m * 64 + k]);
  }
  if (t < 128) { g_part0[t] = 0.f; g_part1[t] = 0.f; }
  g_part2[t] = 0.f;
}

// ---------------- transpose points [b][c][n] -> g_ptb [b,n][c] bf16 ----------------
__global__ __launch_bounds__(256) void k_tpose(const float* __restrict__ points) {
  __shared__ float tile[64][65];
  int b  = blockIdx.x >> 8;
  int n0 = (blockIdx.x & 255) << 6;
#pragma unroll
  for (int r = 0; r < 16; r++) {
    int lin = r * 256 + threadIdx.x;
    int c = lin >> 6, nn = lin & 63;
    tile[c][nn] = points[((size_t)(b * 64 + c)) * N_ALL + n0 + nn];
  }
  __syncthreads();
#pragma unroll
  for (int r = 0; r < 16; r++) {
    int lin = r * 256 + threadIdx.x;
    int nn = lin >> 6, c = lin & 63;
    g_ptb[((size_t)(b * N_ALL + n0 + nn)) * 64 + c] = f2b(tile[c][nn]);
  }
}

// ---------------- KNN: f32 fast filter, u64-exact insert, readlane broadcasts ----------------
__global__ __launch_bounds__(256) void k_knn(const float* __restrict__ xyz) {
#pragma clang fp contract(off)
  int q = blockIdx.x * 4 + (threadIdx.x >> 6);   // 0..8191
  int b = q >> 12, s = q & 4095;
  int lane = threadIdx.x & 63;
  const float* xb = xyz + b * 3 * N_ALL;
  const float* xnb = g_xn + (b << 14);
  float qx = xb[s], qy = xb[N_ALL + s], qz = xb[2 * N_ALL + s];
  float qn = xnb[s];

  unsigned long long list = ~0ULL;    // lanes 0..31: sorted (keybits<<32|idx)
  unsigned long long worst = ~0ULL;   // broadcast copy of list[31]
  float worst_d = __builtin_inff();   // float distance of list[31] (inf while sentinel)

  for (int n0 = 0; n0 < N_ALL; n0 += 256) {
    float d[4];
#pragma unroll
    for (int t = 0; t < 4; t++) {
      int n = n0 + (t << 6) + lane;
      float x = xb[n];
      float y = xb[N_ALL + n];
      float z = xb[2 * N_ALL + n];
      float dt = qx * x + qy * y + qz * z;
      d[t] = (qn + xnb[n]) - 2.0f * dt;
    }
    float md = fminf(fminf(d[0], d[1]), fminf(d[2], d[3]));
    if (__ballot(md <= worst_d)) {
#pragma unroll
      for (int t = 0; t < 4; t++) {
        unsigned du = __float_as_uint(d[t]);
        du ^= ((unsigned)(((int)du) >> 31)) | 0x80000000u;   // order-preserving map
        unsigned long long cand = (((unsigned long long)du) << 32)
                                | (unsigned)(n0 + (t << 6) + lane);
        while (true) {
          unsigned long long ball = __ballot(cand < worst);
          if (!ball) break;
          int j = (int)__builtin_ctzll(ball);
          unsigned long long bk = rdlane64(cand, j);
          if (lane == j) cand = ~0ULL;                 // retire
          unsigned long long up = shflup64(list);
          unsigned long long lm = __ballot(bk < list) & 0xFFFFFFFFULL;
          int pos = (int)__builtin_ctzll(lm);          // bit31 guaranteed set
          if (lane == pos) list = bk;
          else if (lane > pos && lane < 32) list = up;
          worst = rdlane64(list, 31);
          unsigned wh = (unsigned)(worst >> 32);
          worst_d = (wh == 0xFFFFFFFFu) ? __builtin_inff()
                    : __uint_as_float(wh ^ ((wh & 0x80000000u) ? 0x80000000u : 0xFFFFFFFFu));
        }
      }
    }
  }
  if (lane < 32)
    g_knn[(q << 5) | lane] = (unsigned short)(list & 0xFFFF);
}

// ---------------- layer0: gather feats to LDS, MFMA K=96 -> x0 bf16 ----------------
__global__ __launch_bounds__(256) void k_l0(const float* __restrict__ xyz) {
  __shared__ short feats[256][104];   // row 208B: 16B-aligned
  int t = threadIdx.x;
  int p0 = blockIdx.x * 256;
  {
    int p = p0 + t;
    int idx = g_knn[p];
    int s = (p >> 5) & 4095;
    int b = p >> 17;
    const short* src = g_ptb + ((size_t)((b << 14) + idx) << 6);
#pragma unroll
    for (int i = 0; i < 8; i++)
      ((int4*)&feats[t][0])[i] = ((const int4*)src)[i];
    const float* xb = xyz + b * 3 * N_ALL;
    feats[t][64] = f2b(xb[idx] - xb[s]);
    feats[t][65] = f2b(xb[N_ALL + idx] - xb[N_ALL + s]);
    feats[t][66] = f2b(xb[2 * N_ALL + idx] - xb[2 * N_ALL + s]);
#pragma unroll
    for (int c = 67; c < 96; c++) feats[t][c] = 0;
  }
  __syncthreads();
  int lane = t & 63, wv = t >> 6;
  int l15 = lane & 15, quad = lane >> 4;
  bf16x8 A[4][3];
#pragma unroll
  for (int mt = 0; mt < 4; mt++)
#pragma unroll
    for (int kt = 0; kt < 3; kt++)
      A[mt][kt] = *(const bf16x8*)(g_Wb0 + (((mt * 3 + kt) * 64 + lane) << 3));
  f32x4 C[4][4];
#pragma unroll
  for (int mt = 0; mt < 4; mt++)
#pragma unroll
    for (int nt = 0; nt < 4; nt++) C[mt][nt] = 0.f;
#pragma unroll
  for (int kt = 0; kt < 3; kt++)
#pragma unroll
    for (int nt = 0; nt < 4; nt++) {
      bf16x8 B = *(const bf16x8*)(&feats[wv * 64 + nt * 16 + l15][kt * 32 + quad * 8]);
#pragma unroll
      for (int mt = 0; mt < 4; mt++)
        C[mt][nt] = __builtin_amdgcn_mfma_f32_16x16x32_bf16(A[mt][kt], B, C[mt][nt], 0, 0, 0);
    }
#pragma unroll
  for (int mt = 0; mt < 4; mt++)
#pragma unroll
    for (int nt = 0; nt < 4; nt++) {
      int p = p0 + wv * 64 + nt * 16 + l15;
      int c0 = mt * 16 + quad * 4;
      short4 o;
      o.x = f2b(C[mt][nt][0]); o.y = f2b(C[mt][nt][1]);
      o.z = f2b(C[mt][nt][2]); o.w = f2b(C[mt][nt][3]);
      *(short4*)(g_x0b + ((size_t)p << 6) + c0) = o;
    }
}

// ---------------- layer1: BN0+leaky on x0 frags, MFMA K=64 -> x1 bf16 ----------------
__global__ __launch_bounds__(256) void k_l1(const float* __restrict__ g0,
                                            const float* __restrict__ b0) {
  __shared__ float scA[64], shA[64];
  int t = threadIdx.x;
  if (t < 64) {
    float m = g_part0[t] / P_TOTF;
    float v = g_part0[64 + t] / P_TOTF - m * m;
    float sc = g0[t] / sqrtf(v + EPSV);
    scA[t] = sc; shA[t] = b0[t] - m * sc;
  }
  __syncthreads();
  int lane = t & 63, wv = t >> 6;
  int l15 = lane & 15, quad = lane >> 4;
  int p0 = blockIdx.x * 256 + wv * 64;
  float scv[2][8], shv[2][8];
#pragma unroll
  for (int kt = 0; kt < 2; kt++)
#pragma unroll
    for (int j = 0; j < 8; j++) {
      int c = kt * 32 + quad * 8 + j;
      scv[kt][j] = scA[c]; shv[kt][j] = shA[c];
    }
  bf16x8 A[4][2];
#pragma unroll
  for (int mt = 0; mt < 4; mt++)
#pragma unroll
    for (int kt = 0; kt < 2; kt++)
      A[mt][kt] = *(const bf16x8*)(g_Wb1 + (((mt * 2 + kt) * 64 + lane) << 3));
  f32x4 C[4][4];
#pragma unroll
  for (int mt = 0; mt < 4; mt++)
#pragma unroll
    for (int nt = 0; nt < 4; nt++) C[mt][nt] = 0.f;
#pragma unroll
  for (int kt = 0; kt < 2; kt++)
#pragma unroll
    for (int nt = 0; nt < 4; nt++) {
      const short* src = g_x0b + (((size_t)(p0 + nt * 16 + l15)) << 6) + kt * 32 + quad * 8;
      bf16x8 raw = *(const bf16x8*)src;
      bf16x8 B;
#pragma unroll
      for (int j = 0; j < 8; j++) {
        float a = b2f(raw[j]) * scv[kt][j] + shv[kt][j];
        a = fmaxf(a, 0.1f * a);
        B[j] = f2b(a);
      }
#pragma unroll
      for (int mt = 0; mt < 4; mt++)
        C[mt][nt] = __builtin_amdgcn_mfma_f32_16x16x32_bf16(A[mt][kt], B, C[mt][nt], 0, 0, 0);
    }
#pragma unroll
  for (int mt = 0; mt < 4; mt++)
#pragma unroll
    for (int nt = 0; nt < 4; nt++) {
      int p = p0 + nt * 16 + l15;
      int c0 = mt * 16 + quad * 4;
      short4 o;
      o.x = f2b(C[mt][nt][0]); o.y = f2b(C[mt][nt][1]);
      o.z = f2b(C[mt][nt][2]); o.w = f2b(C[mt][nt][3]);
      *(short4*)(g_x1b + ((size_t)p << 6) + c0) = o;
    }
}

// ---------------- layer2: BN1+leaky on x1 frags, MFMA K=64 M=128 -> x2 bf16 ----------------
__global__ __launch_bounds__(256) void k_l2(const float* __restrict__ g1,
                                            const float* __restrict__ b1) {
  __shared__ float scA[64], shA[64];
  int t = threadIdx.x;
  if (t < 64) {
    float m = g_part1[t] / P_TOTF;
    float v = g_part1[64 + t] / P_TOTF - m * m;
    float sc = g1[t] / sqrtf(v + EPSV);
    scA[t] = sc; shA[t] = b1[t] - m * sc;
  }
  __syncthreads();
  int lane = t & 63, wv = t >> 6;
  int l15 = lane & 15, quad = lane >> 4;
  int chh = wv & 1;                      // channel half
  int p0 = blockIdx.x * 128 + (wv >> 1) * 64;
  float scv[2][8], shv[2][8];
#pragma unroll
  for (int kt = 0; kt < 2; kt++)
#pragma unroll
    for (int j = 0; j < 8; j++) {
      int c = kt * 32 + quad * 8 + j;
      scv[kt][j] = scA[c]; shv[kt][j] = shA[c];
    }
  bf16x8 A[4][2];
#pragma unroll
  for (int mt = 0; mt < 4; mt++)
#pragma unroll
    for (int kt = 0; kt < 2; kt++)
      A[mt][kt] = *(const bf16x8*)(g_Wb2 + ((((4 * chh + mt) * 2 + kt) * 64 + lane) << 3));
  f32x4 C[4][4];
#pragma unroll
  for (int mt = 0; mt < 4; mt++)
#pragma unroll
    for (int nt = 0; nt < 4; nt++) C[mt][nt] = 0.f;
#pragma unroll
  for (int kt = 0; kt < 2; kt++)
#pragma unroll
    for (int nt = 0; nt < 4; nt++) {
      const short* src = g_x1b + (((size_t)(p0 + nt * 16 + l15)) << 6) + kt * 32 + quad * 8;
      bf16x8 raw = *(const bf16x8*)src;
      bf16x8 B;
#pragma unroll
      for (int j = 0; j < 8; j++) {
        float a = b2f(raw[j]) * scv[kt][j] + shv[kt][j];
        a = fmaxf(a, 0.1f * a);
        B[j] = f2b(a);
      }
#pragma unroll
      for (int mt = 0; mt < 4; mt++)
        C[mt][nt] = __builtin_amdgcn_mfma_f32_16x16x32_bf16(A[mt][kt], B, C[mt][nt], 0, 0, 0);
    }
#pragma unroll
  for (int mt = 0; mt < 4; mt++)
#pragma unroll
    for (int nt = 0; nt < 4; nt++) {
      int p = p0 + nt * 16 + l15;
      int c0 = (4 * chh + mt) * 16 + quad * 4;
      short4 o;
      o.x = f2b(C[mt][nt][0]); o.y = f2b(C[mt][nt][1]);
      o.z = f2b(C[mt][nt][2]); o.w = f2b(C[mt][nt][3]);
      *(short4*)(g_x2b + ((size_t)p << 7) + c0) = o;
    }
}

// ---------------- streaming stats over bf16 [p][64] ----------------
__global__ __launch_bounds__(256) void k_red64(const short* __restrict__ x,
                                               float* __restrict__ part) {
  int t = threadIdx.x;
  int cl = t & 31, pr = t >> 5;
  float s0 = 0.f, s1 = 0.f, q0 = 0.f, q1 = 0.f;
  int pbase = blockIdx.x * 1024;
  for (int i = 0; i < 128; i++) {
    int p = pbase + pr + i * 8;
    unsigned d = *(const unsigned*)(x + ((size_t)p << 6) + cl * 2);
    float a = b2f((short)(d & 0xFFFF));
    float b = b2f((short)(d >> 16));
    s0 += a; q0 = fmaf(a, a, q0);
    s1 += b; q1 = fmaf(b, b, q1);
  }
  __shared__ float sm[8][64], sq[8][64];
  sm[pr][cl * 2] = s0; sm[pr][cl * 2 + 1] = s1;
  sq[pr][cl * 2] = q0; sq[pr][cl * 2 + 1] = q1;
  __syncthreads();
  if (t < 64) {
    float S = 0.f, Q = 0.f;
#pragma unroll
    for (int r = 0; r < 8; r++) { S += sm[r][t]; Q += sq[r][t]; }
    atomicAdd(part + t, S); atomicAdd(part + 64 + t, Q);
  }
}

// ---------------- streaming stats over bf16 [p][128] ----------------
__global__ __launch_bounds__(256) void k_red128(const short* __restrict__ x,
                                                float* __restrict__ part) {
  int t = threadIdx.x;
  int cl = t & 63, pr = t >> 6;
  float s0 = 0.f, s1 = 0.f, q0 = 0.f, q1 = 0.f;
  int pbase = blockIdx.x * 1024;
  for (int i = 0; i < 256; i++) {
    int p = pbase + pr + i * 4;
    unsigned d = *(const unsigned*)(x + ((size_t)p << 7) + cl * 2);
    float a = b2f((short)(d & 0xFFFF));
    float b = b2f((short)(d >> 16));
    s0 += a; q0 = fmaf(a, a, q0);
    s1 += b; q1 = fmaf(b, b, q1);
  }
  __shared__ float sm[4][128], sq[4][128];
  sm[pr][cl * 2] = s0; sm[pr][cl * 2 + 1] = s1;
  sq[pr][cl * 2] = q0; sq[pr][cl * 2 + 1] = q1;
  __syncthreads();
  if (t < 128) {
    float S = 0.f, Q = 0.f;
#pragma unroll
    for (int r = 0; r < 4; r++) { S += sm[r][t]; Q += sq[r][t]; }
    atomicAdd(part + t, S); atomicAdd(part + 128 + t, Q);
  }
}

// ---------------- epilogue: max/min over k from x2, BN2+leaky, write f32 ----------------
__global__ __launch_bounds__(256) void k_epi(const float* __restrict__ g2,
                                             const float* __restrict__ b2,
                                             float* __restrict__ out) {
  __shared__ float scA[128], shA[128];
  int t = threadIdx.x;
  if (t < 128) {
    float m = g_part2[t] / P_TOTF;
    float v = g_part2[128 + t] / P_TOTF - m * m;
    float sc = g2[t] / sqrtf(v + EPSV);
    scA[t] = sc; shA[t] = b2[t] - m * sc;
  }
  __syncthreads();
  int c = t & 127, sl = t >> 7;
  int sg = blockIdx.x * 2 + sl;                  // 0..8191
  size_t base = (((size_t)sg) << 12) + c;        // (sg*32)*128 + c
  float mx = -3.4e38f, mn = 3.4e38f;
#pragma unroll
  for (int k = 0; k < 32; k++) {
    float v = b2f(g_x2b[base + (size_t)k * 128]);
    mx = fmaxf(mx, v); mn = fminf(mn, v);
  }
  float sc = scA[c];
  float a = (sc >= 0.f ? mx : mn) * sc + shA[c];
  a = fmaxf(a, 0.1f * a);
  int b = sg >> 12, s = sg & 4095;
  out[24576 + (((b * 128 + c) << 12) | s)] = a;
}

extern "C" void kernel_launch(void* const* d_in, const int* in_sizes, int n_in,
                              void* d_out, int out_size, void* d_ws, size_t ws_size,
                              hipStream_t stream) {
  (void)in_sizes; (void)n_in; (void)out_size; (void)d_ws; (void)ws_size;
  const float* xyz    = (const float*)d_in[0];
  const float* points = (const float*)d_in[1];
  const float* W0     = (const float*)d_in[2];
  const float* W1     = (const float*)d_in[3];
  const float* W2     = (const float*)d_in[4];
  const float* g0     = (const float*)d_in[5];
  const float* b0     = (const float*)d_in[6];
  const float* g1     = (const float*)d_in[7];
  const float* b1     = (const float*)d_in[8];
  const float* g2     = (const float*)d_in[9];
  const float* b2     = (const float*)d_in[10];
  float* out = (float*)d_out;

  short *x0b, *x1b, *x2b; float *part0, *part1, *part2;
  hipGetSymbolAddress((void**)&x0b,   HIP_SYMBOL(g_x0b));
  hipGetSymbolAddress((void**)&x1b,   HIP_SYMBOL(g_x1b));
  hipGetSymbolAddress((void**)&x2b,   HIP_SYMBOL(g_x2b));
  hipGetSymbolAddress((void**)&part0, HIP_SYMBOL(g_part0));
  hipGetSymbolAddress((void**)&part1, HIP_SYMBOL(g_part1));
  hipGetSymbolAddress((void**)&part2, HIP_SYMBOL(g_part2));

  hipLaunchKernelGGL(k_init,   dim3(128),  dim3(256), 0, stream, xyz, out);
  hipLaunchKernelGGL(k_prep,   dim3(1),    dim3(256), 0, stream, W0, W1, W2);
  hipLaunchKernelGGL(k_tpose,  dim3(512),  dim3(256), 0, stream, points);
  hipLaunchKernelGGL(k_knn,    dim3(2048), dim3(256), 0, stream, xyz);
  hipLaunchKernelGGL(k_l0,     dim3(1024), dim3(256), 0, stream, xyz);
  hipLaunchKernelGGL(k_red64,  dim3(256),  dim3(256), 0, stream, x0b, part0);
  hipLaunchKernelGGL(k_l1,     dim3(1024), dim3(256), 0, stream, g0, b0);
  hipLaunchKernelGGL(k_red64,  dim3(256),  dim3(256), 0, stream, x1b, part1);
  hipLaunchKernelGGL(k_l2,     dim3(2048), dim3(256), 0, stream, g1, b1);
  hipLaunchKernelGGL(k_red128, dim3(256),  dim3(256), 0, stream, x2b, part2);
  hipLaunchKernelGGL(k_epi,    dim3(4096), dim3(256), 0, stream, g2, b2, out);
}

// Round 12
// 382.103 us; speedup vs baseline: 1.1512x; 1.0299x over previous
//
#include <hip/hip_runtime.h>
#include <stdint.h>

#define N_ALL   16384
#define NPOINT  4096
#define KNN_K   32
#define BATCH   2
#define P_TOT   (BATCH*NPOINT*KNN_K)   /* 262144 */
#define P_TOTF  262144.0f
#define EPSV    1e-5f

typedef __attribute__((ext_vector_type(8))) short bf16x8;
typedef __attribute__((ext_vector_type(4))) float f32x4;

// ---- all scratch in module-static device memory; d_ws untouched ----
__device__ unsigned short g_knn[P_TOT];                                   // 512 KB
__device__ __attribute__((aligned(16))) float g_pxyzn[BATCH*N_ALL*4];     // 512 KB (x,y,z,|x|^2)
__device__ __attribute__((aligned(16))) short g_ptb[BATCH*N_ALL*64];      // 4 MB  [b,n][64c] bf16
__device__ __attribute__((aligned(16))) short g_x0b[(size_t)P_TOT*64];    // 32 MB [p][64] bf16
__device__ __attribute__((aligned(16))) short g_x1b[(size_t)P_TOT*64];    // 32 MB
__device__ __attribute__((aligned(16))) short g_x2b[(size_t)P_TOT*128];   // 64 MB
__device__ __attribute__((aligned(16))) short g_Wb0[4*3*64*8];            // swizzled A-frags
__device__ __attribute__((aligned(16))) short g_Wb1[4*2*64*8];
__device__ __attribute__((aligned(16))) short g_Wb2[8*2*64*8];
__device__ float g_part0[128], g_part1[128], g_part2[256];

__device__ __forceinline__ float b2f(short s) {
  union { unsigned u; float f; } v; v.u = ((unsigned)(unsigned short)s) << 16; return v.f;
}
__device__ __forceinline__ short f2b(float f) {
  union { float f; unsigned u; } v; v.f = f;
  unsigned u = v.u;
  u += 0x7FFFu + ((u >> 16) & 1u);
  return (short)(u >> 16);
}
__device__ __forceinline__ unsigned long long shflup64(unsigned long long v) {
  int lo = __shfl_up((int)(unsigned)(v & 0xFFFFFFFFULL), 1, 64);
  int hi = __shfl_up((int)(unsigned)(v >> 32), 1, 64);
  return (((unsigned long long)(unsigned)hi) << 32) | (unsigned)lo;
}
__device__ __forceinline__ unsigned long long rdlane64(unsigned long long v, int j) {
  unsigned hi = (unsigned)__builtin_amdgcn_readlane((int)(unsigned)(v >> 32), j);
  unsigned lo = (unsigned)__builtin_amdgcn_readlane((int)(unsigned)(v & 0xFFFFFFFFULL), j);
  return (((unsigned long long)hi) << 32) | lo;
}

// ---------------- setup: tpose (blk<512) | copy+pack (512..639) | wprep (640) ----------------
__global__ __launch_bounds__(256) void k_setup(const float* __restrict__ xyz,
                                               const float* __restrict__ points,
                                               const float* __restrict__ W0,
                                               const float* __restrict__ W1,
                                               const float* __restrict__ W2,
                                               float* __restrict__ out) {
#pragma clang fp contract(off)
  __shared__ float tile[64][65];
  int blk = blockIdx.x;
  int t = threadIdx.x;
  if (blk < 512) {
    int b  = blk >> 8;
    int n0 = (blk & 255) << 6;
#pragma unroll
    for (int r = 0; r < 16; r++) {
      int lin = r * 256 + t;
      int c = lin >> 6, nn = lin & 63;
      tile[c][nn] = points[((size_t)(b * 64 + c)) * N_ALL + n0 + nn];
    }
    __syncthreads();
#pragma unroll
    for (int r = 0; r < 16; r++) {
      int lin = r * 256 + t;
      int nn = lin >> 6, c = lin & 63;
      g_ptb[((size_t)(b * N_ALL + n0 + nn)) * 64 + c] = f2b(tile[c][nn]);
    }
  } else if (blk < 640) {
    int i = (blk - 512) * 256 + t;   // < 32768
    if (i < 24576) {
      int s = i & 4095;
      int c = (i >> 12) % 3;
      int b = i / 12288;
      out[i] = xyz[(b * 3 + c) * N_ALL + s];
    }
    int b = i >> 14, n = i & 16383;
    const float* xb = xyz + b * 3 * N_ALL;
    float x = xb[n], y = xb[N_ALL + n], z = xb[2 * N_ALL + n];
    float4 p; p.x = x; p.y = y; p.z = z; p.w = x * x + y * y + z * z;
    ((float4*)g_pxyzn)[i] = p;
  } else {
    for (int i = t; i < 4 * 3 * 64 * 8; i += 256) {
      int j = i & 7, lane = (i >> 3) & 63, rest = i >> 9;
      int kt = rest % 3, mt = rest / 3;
      int m = 16 * mt + (lane & 15);
      int k = 32 * kt + (lane >> 4) * 8 + j;
      float v = 0.f;
      if (k < 64) v = W0[m * 67 + 3 + k];
      else if (k < 67) v = W0[m * 67 + (k - 64)];
      g_Wb0[i] = f2b(v);
    }
    for (int i = t; i < 4 * 2 * 64 * 8; i += 256) {
      int j = i & 7, lane = (i >> 3) & 63;
      int kt = (i >> 9) & 1, mt = i >> 10;
      int m = 16 * mt + (lane & 15);
      int k = 32 * kt + (lane >> 4) * 8 + j;
      g_Wb1[i] = f2b(W1[m * 64 + k]);
    }
    for (int i = t; i < 8 * 2 * 64 * 8; i += 256) {
      int j = i & 7, lane = (i >> 3) & 63;
      int kt = (i >> 9) & 1, mt = i >> 10;
      int m = 16 * mt + (lane & 15);
      int k = 32 * kt + (lane >> 4) * 8 + j;
      g_Wb2[i] = f2b(W2[m * 64 + k]);
    }
    if (t < 128) { g_part0[t] = 0.f; g_part1[t] = 0.f; }
    g_part2[t] = 0.f;
  }
}

// ---------------- KNN: float4 stream, 8-pt chunks, exact u64 insert ----------------
__global__ __launch_bounds__(256) void k_knn() {
#pragma clang fp contract(off)
  int q = blockIdx.x * 4 + (threadIdx.x >> 6);   // 0..8191
  int b = q >> 12, s = q & 4095;
  int lane = threadIdx.x & 63;
  const float4* pb = (const float4*)g_pxyzn + (b << 14);
  float4 qp = pb[s];
  float qx = qp.x, qy = qp.y, qz = qp.z, qn = qp.w;

  unsigned long long list = ~0ULL;    // lanes 0..31: sorted (keybits<<32|idx)
  unsigned long long worst = ~0ULL;   // broadcast copy of list[31]
  float worst_d = __builtin_inff();

  for (int n0 = 0; n0 < N_ALL; n0 += 512) {
    float d[8];
#pragma unroll
    for (int t = 0; t < 8; t++) {
      float4 p = pb[n0 + (t << 6) + lane];
      float dt = (qx * p.x + qy * p.y) + qz * p.z;        // contract off: exact ref order
      d[t] = __builtin_fmaf(-2.0f, dt, qn + p.w);         // == (qn+xn) - 2*dt exactly
    }
    float md = fminf(fminf(fminf(d[0], d[1]), fminf(d[2], d[3])),
                     fminf(fminf(d[4], d[5]), fminf(d[6], d[7])));
    if (__ballot(md <= worst_d)) {
#pragma unroll
      for (int t = 0; t < 8; t++) {
        unsigned du = __float_as_uint(d[t]);
        du ^= ((unsigned)(((int)du) >> 31)) | 0x80000000u;   // order-preserving map
        unsigned long long cand = (((unsigned long long)du) << 32)
                                | (unsigned)(n0 + (t << 6) + lane);
        while (true) {
          unsigned long long ball = __ballot(cand < worst);
          if (!ball) break;
          int j = (int)__builtin_ctzll(ball);
          unsigned long long bk = rdlane64(cand, j);
          if (lane == j) cand = ~0ULL;                 // retire
          unsigned long long up = shflup64(list);
          unsigned long long lm = __ballot(bk < list) & 0xFFFFFFFFULL;
          int pos = (int)__builtin_ctzll(lm);          // bit31 guaranteed set
          if (lane == pos) list = bk;
          else if (lane > pos && lane < 32) list = up;
          worst = rdlane64(list, 31);
          unsigned wh = (unsigned)(worst >> 32);
          worst_d = (wh == 0xFFFFFFFFu) ? __builtin_inff()
                    : __uint_as_float(wh ^ ((wh & 0x80000000u) ? 0x80000000u : 0xFFFFFFFFu));
        }
      }
    }
  }
  if (lane < 32)
    g_knn[(q << 5) | lane] = (unsigned short)(list & 0xFFFF);
}

// ---------------- layer0: gather feats to LDS, MFMA K=96 -> x0 bf16 ----------------
__global__ __launch_bounds__(256) void k_l0(const float* __restrict__ xyz) {
  __shared__ short feats[256][104];   // row 208B: 16B-aligned
  int t = threadIdx.x;
  int p0 = blockIdx.x * 256;
  {
    int p = p0 + t;
    int idx = g_knn[p];
    int s = (p >> 5) & 4095;
    int b = p >> 17;
    const short* src = g_ptb + ((size_t)((b << 14) + idx) << 6);
#pragma unroll
    for (int i = 0; i < 8; i++)
      ((int4*)&feats[t][0])[i] = ((const int4*)src)[i];
    const float* xb = xyz + b * 3 * N_ALL;
    feats[t][64] = f2b(xb[idx] - xb[s]);
    feats[t][65] = f2b(xb[N_ALL + idx] - xb[N_ALL + s]);
    feats[t][66] = f2b(xb[2 * N_ALL + idx] - xb[2 * N_ALL + s]);
#pragma unroll
    for (int c = 67; c < 96; c++) feats[t][c] = 0;
  }
  __syncthreads();
  int lane = t & 63, wv = t >> 6;
  int l15 = lane & 15, quad = lane >> 4;
  bf16x8 A[4][3];
#pragma unroll
  for (int mt = 0; mt < 4; mt++)
#pragma unroll
    for (int kt = 0; kt < 3; kt++)
      A[mt][kt] = *(const bf16x8*)(g_Wb0 + (((mt * 3 + kt) * 64 + lane) << 3));
  f32x4 C[4][4];
#pragma unroll
  for (int mt = 0; mt < 4; mt++)
#pragma unroll
    for (int nt = 0; nt < 4; nt++) C[mt][nt] = 0.f;
#pragma unroll
  for (int kt = 0; kt < 3; kt++)
#pragma unroll
    for (int nt = 0; nt < 4; nt++) {
      bf16x8 B = *(const bf16x8*)(&feats[wv * 64 + nt * 16 + l15][kt * 32 + quad * 8]);
#pragma unroll
      for (int mt = 0; mt < 4; mt++)
        C[mt][nt] = __builtin_amdgcn_mfma_f32_16x16x32_bf16(A[mt][kt], B, C[mt][nt], 0, 0, 0);
    }
#pragma unroll
  for (int mt = 0; mt < 4; mt++)
#pragma unroll
    for (int nt = 0; nt < 4; nt++) {
      int p = p0 + wv * 64 + nt * 16 + l15;
      int c0 = mt * 16 + quad * 4;
      short4 o;
      o.x = f2b(C[mt][nt][0]); o.y = f2b(C[mt][nt][1]);
      o.z = f2b(C[mt][nt][2]); o.w = f2b(C[mt][nt][3]);
      *(short4*)(g_x0b + ((size_t)p << 6) + c0) = o;
    }
}

// ---------------- layer1: BN0+leaky on x0 frags, MFMA K=64 -> x1 bf16 ----------------
__global__ __launch_bounds__(256) void k_l1(const float* __restrict__ g0,
                                            const float* __restrict__ b0) {
  __shared__ float scA[64], shA[64];
  int t = threadIdx.x;
  if (t < 64) {
    float m = g_part0[t] / P_TOTF;
    float v = g_part0[64 + t] / P_TOTF - m * m;
    float sc = g0[t] / sqrtf(v + EPSV);
    scA[t] = sc; shA[t] = b0[t] - m * sc;
  }
  __syncthreads();
  int lane = t & 63, wv = t >> 6;
  int l15 = lane & 15, quad = lane >> 4;
  int p0 = blockIdx.x * 256 + wv * 64;
  float scv[2][8], shv[2][8];
#pragma unroll
  for (int kt = 0; kt < 2; kt++)
#pragma unroll
    for (int j = 0; j < 8; j++) {
      int c = kt * 32 + quad * 8 + j;
      scv[kt][j] = scA[c]; shv[kt][j] = shA[c];
    }
  bf16x8 A[4][2];
#pragma unroll
  for (int mt = 0; mt < 4; mt++)
#pragma unroll
    for (int kt = 0; kt < 2; kt++)
      A[mt][kt] = *(const bf16x8*)(g_Wb1 + (((mt * 2 + kt) * 64 + lane) << 3));
  f32x4 C[4][4];
#pragma unroll
  for (int mt = 0; mt < 4; mt++)
#pragma unroll
    for (int nt = 0; nt < 4; nt++) C[mt][nt] = 0.f;
#pragma unroll
  for (int kt = 0; kt < 2; kt++)
#pragma unroll
    for (int nt = 0; nt < 4; nt++) {
      const short* src = g_x0b + (((size_t)(p0 + nt * 16 + l15)) << 6) + kt * 32 + quad * 8;
      bf16x8 raw = *(const bf16x8*)src;
      bf16x8 B;
#pragma unroll
      for (int j = 0; j < 8; j++) {
        float a = b2f(raw[j]) * scv[kt][j] + shv[kt][j];
        a = fmaxf(a, 0.1f * a);
        B[j] = f2b(a);
      }
#pragma unroll
      for (int mt = 0; mt < 4; mt++)
        C[mt][nt] = __builtin_amdgcn_mfma_f32_16x16x32_bf16(A[mt][kt], B, C[mt][nt], 0, 0, 0);
    }
#pragma unroll
  for (int mt = 0; mt < 4; mt++)
#pragma unroll
    for (int nt = 0; nt < 4; nt++) {
      int p = p0 + nt * 16 + l15;
      int c0 = mt * 16 + quad * 4;
      short4 o;
      o.x = f2b(C[mt][nt][0]); o.y = f2b(C[mt][nt][1]);
      o.z = f2b(C[mt][nt][2]); o.w = f2b(C[mt][nt][3]);
      *(short4*)(g_x1b + ((size_t)p << 6) + c0) = o;
    }
}

// ---------------- layer2: BN1+leaky on x1 frags, MFMA K=64 M=128 -> x2 bf16 ----------------
__global__ __launch_bounds__(256) void k_l2(const float* __restrict__ g1,
                                            const float* __restrict__ b1) {
  __shared__ float scA[64], shA[64];
  int t = threadIdx.x;
  if (t < 64) {
    float m = g_part1[t] / P_TOTF;
    float v = g_part1[64 + t] / P_TOTF - m * m;
    float sc = g1[t] / sqrtf(v + EPSV);
    scA[t] = sc; shA[t] = b1[t] - m * sc;
  }
  __syncthreads();
  int lane = t & 63, wv = t >> 6;
  int l15 = lane & 15, quad = lane >> 4;
  int chh = wv & 1;                      // channel half
  int p0 = blockIdx.x * 128 + (wv >> 1) * 64;
  float scv[2][8], shv[2][8];
#pragma unroll
  for (int kt = 0; kt < 2; kt++)
#pragma unroll
    for (int j = 0; j < 8; j++) {
      int c = kt * 32 + quad * 8 + j;
      scv[kt][j] = scA[c]; shv[kt][j] = shA[c];
    }
  bf16x8 A[4][2];
#pragma unroll
  for (int mt = 0; mt < 4; mt++)
#pragma unroll
    for (int kt = 0; kt < 2; kt++)
      A[mt][kt] = *(const bf16x8*)(g_Wb2 + ((((4 * chh + mt) * 2 + kt) * 64 + lane) << 3));
  f32x4 C[4][4];
#pragma unroll
  for (int mt = 0; mt < 4; mt++)
#pragma unroll
    for (int nt = 0; nt < 4; nt++) C[mt][nt] = 0.f;
#pragma unroll
  for (int kt = 0; kt < 2; kt++)
#pragma unroll
    for (int nt = 0; nt < 4; nt++) {
      const short* src = g_x1b + (((size_t)(p0 + nt * 16 + l15)) << 6) + kt * 32 + quad * 8;
      bf16x8 raw = *(const bf16x8*)src;
      bf16x8 B;
#pragma unroll
      for (int j = 0; j < 8; j++) {
        float a = b2f(raw[j]) * scv[kt][j] + shv[kt][j];
        a = fmaxf(a, 0.1f * a);
        B[j] = f2b(a);
      }
#pragma unroll
      for (int mt = 0; mt < 4; mt++)
        C[mt][nt] = __builtin_amdgcn_mfma_f32_16x16x32_bf16(A[mt][kt], B, C[mt][nt], 0, 0, 0);
    }
#pragma unroll
  for (int mt = 0; mt < 4; mt++)
#pragma unroll
    for (int nt = 0; nt < 4; nt++) {
      int p = p0 + nt * 16 + l15;
      int c0 = (4 * chh + mt) * 16 + quad * 4;
      short4 o;
      o.x = f2b(C[mt][nt][0]); o.y = f2b(C[mt][nt][1]);
      o.z = f2b(C[mt][nt][2]); o.w = f2b(C[mt][nt][3]);
      *(short4*)(g_x2b + ((size_t)p << 7) + c0) = o;
    }
}

// ---------------- streaming stats over bf16 [p][64] ----------------
__global__ __launch_bounds__(256) void k_red64(const short* __restrict__ x,
                                               float* __restrict__ part) {
  int t = threadIdx.x;
  int cl = t & 31, pr = t >> 5;
  float s0 = 0.f, s1 = 0.f, q0 = 0.f, q1 = 0.f;
  int pbase = blockIdx.x * 1024;
  for (int i = 0; i < 128; i++) {
    int p = pbase + pr + i * 8;
    unsigned d = *(const unsigned*)(x + ((size_t)p << 6) + cl * 2);
    float a = b2f((short)(d & 0xFFFF));
    float b = b2f((short)(d >> 16));
    s0 += a; q0 = fmaf(a, a, q0);
    s1 += b; q1 = fmaf(b, b, q1);
  }
  __shared__ float sm[8][64], sq[8][64];
  sm[pr][cl * 2] = s0; sm[pr][cl * 2 + 1] = s1;
  sq[pr][cl * 2] = q0; sq[pr][cl * 2 + 1] = q1;
  __syncthreads();
  if (t < 64) {
    float S = 0.f, Q = 0.f;
#pragma unroll
    for (int r = 0; r < 8; r++) { S += sm[r][t]; Q += sq[r][t]; }
    atomicAdd(part + t, S); atomicAdd(part + 64 + t, Q);
  }
}

// ---------------- streaming stats over bf16 [p][128] ----------------
__global__ __launch_bounds__(256) void k_red128(const short* __restrict__ x,
                                                float* __restrict__ part) {
  int t = threadIdx.x;
  int cl = t & 63, pr = t >> 6;
  float s0 = 0.f, s1 = 0.f, q0 = 0.f, q1 = 0.f;
  int pbase = blockIdx.x * 1024;
  for (int i = 0; i < 256; i++) {
    int p = pbase + pr + i * 4;
    unsigned d = *(const unsigned*)(x + ((size_t)p << 7) + cl * 2);
    float a = b2f((short)(d & 0xFFFF));
    float b = b2f((short)(d >> 16));
    s0 += a; q0 = fmaf(a, a, q0);
    s1 += b; q1 = fmaf(b, b, q1);
  }
  __shared__ float sm[4][128], sq[4][128];
  sm[pr][cl * 2] = s0; sm[pr][cl * 2 + 1] = s1;
  sq[pr][cl * 2] = q0; sq[pr][cl * 2 + 1] = q1;
  __syncthreads();
  if (t < 128) {
    float S = 0.f, Q = 0.f;
#pragma unroll
    for (int r = 0; r < 4; r++) { S += sm[r][t]; Q += sq[r][t]; }
    atomicAdd(part + t, S); atomicAdd(part + 128 + t, Q);
  }
}

// ---------------- epilogue: max/min over k from x2, BN2+leaky, write f32 ----------------
__global__ __launch_bounds__(256) void k_epi(const float* __restrict__ g2,
                                             const float* __restrict__ b2,
                                             float* __restrict__ out) {
  __shared__ float scA[128], shA[128];
  int t = threadIdx.x;
  if (t < 128) {
    float m = g_part2[t] / P_TOTF;
    float v = g_part2[128 + t] / P_TOTF - m * m;
    float sc = g2[t] / sqrtf(v + EPSV);
    scA[t] = sc; shA[t] = b2[t] - m * sc;
  }
  __syncthreads();
  int c = t & 127, sl = t >> 7;
  int sg = blockIdx.x * 2 + sl;                  // 0..8191
  size_t base = (((size_t)sg) << 12) + c;        // (sg*32)*128 + c
  float mx = -3.4e38f, mn = 3.4e38f;
#pragma unroll
  for (int k = 0; k < 32; k++) {
    float v = b2f(g_x2b[base + (size_t)k * 128]);
    mx = fmaxf(mx, v); mn = fminf(mn, v);
  }
  float sc = scA[c];
  float a = (sc >= 0.f ? mx : mn) * sc + shA[c];
  a = fmaxf(a, 0.1f * a);
  int b = sg >> 12, s = sg & 4095;
  out[24576 + (((b * 128 + c) << 12) | s)] = a;
}

extern "C" void kernel_launch(void* const* d_in, const int* in_sizes, int n_in,
                              void* d_out, int out_size, void* d_ws, size_t ws_size,
                              hipStream_t stream) {
  (void)in_sizes; (void)n_in; (void)out_size; (void)d_ws; (void)ws_size;
  const float* xyz    = (const float*)d_in[0];
  const float* points = (const float*)d_in[1];
  const float* W0     = (const float*)d_in[2];
  const float* W1     = (const float*)d_in[3];
  const float* W2     = (const float*)d_in[4];
  const float* g0     = (const float*)d_in[5];
  const float* b0     = (const float*)d_in[6];
  const float* g1     = (const float*)d_in[7];
  const float* b1     = (const float*)d_in[8];
  const float* g2     = (const float*)d_in[9];
  const float* b2     = (const float*)d_in[10];
  float* out = (float*)d_out;

  short *x0b, *x1b, *x2b; float *part0, *part1, *part2;
  hipGetSymbolAddress((void**)&x0b,   HIP_SYMBOL(g_x0b));
  hipGetSymbolAddress((void**)&x1b,   HIP_SYMBOL(g_x1b));
  hipGetSymbolAddress((void**)&x2b,   HIP_SYMBOL(g_x2b));
  hipGetSymbolAddress((void**)&part0, HIP_SYMBOL(g_part0));
  hipGetSymbolAddress((void**)&part1, HIP_SYMBOL(g_part1));
  hipGetSymbolAddress((void**)&part2, HIP_SYMBOL(g_part2));

  hipLaunchKernelGGL(k_setup,  dim3(641),  dim3(256), 0, stream, xyz, points, W0, W1, W2, out);
  hipLaunchKernelGGL(k_knn,    dim3(2048), dim3(256), 0, stream);
  hipLaunchKernelGGL(k_l0,     dim3(1024), dim3(256), 0, stream, xyz);
  hipLaunchKernelGGL(k_red64,  dim3(256),  dim3(256), 0, stream, x0b, part0);
  hipLaunchKernelGGL(k_l1,     dim3(1024), dim3(256), 0, stream, g0, b0);
  hipLaunchKernelGGL(k_red64,  dim3(256),  dim3(256), 0, stream, x1b, part1);
  hipLaunchKernelGGL(k_l2,     dim3(2048), dim3(256), 0, stream, g1, b1);
  hipLaunchKernelGGL(k_red128, dim3(256),  dim3(256), 0, stream, x2b, part2);
  hipLaunchKernelGGL(k_epi,    dim3(4096), dim3(256), 0, stream, g2, b2, out);
}